// Round 17
// baseline (235.078 us; speedup 1.0000x reference)
//
#include <hip/hip_runtime.h>

#define N_NODES 100000
#define N_EDGES 1600000
#define N_GRAPHS 64
#define IN_CH 15
#define HID 128
#define NCLS 11

// bucketed CSR geometry
#define NBUCK 196            // ceil(100000 / 512), bucket = dst >> 9
#define NBF 512              // partition blocks
#define EPB (N_EDGES / NBF)  // 3125 edges per block

using short8 = __attribute__((ext_vector_type(8))) short;
using f32x4 = __attribute__((ext_vector_type(4))) float;
using f32x2 = __attribute__((ext_vector_type(2))) float;

// ---- bf16 pack/unpack (RNE) ----
__device__ __forceinline__ unsigned short f2bf(float f) {
    unsigned u = __builtin_bit_cast(unsigned, f);
    u += 0x7FFF + ((u >> 16) & 1);
    return (unsigned short)(u >> 16);
}
__device__ __forceinline__ unsigned packbf(float a, float b) {
    return (unsigned)f2bf(a) | ((unsigned)f2bf(b) << 16);
}
__device__ __forceinline__ float2 unpackbf(unsigned v) {
    float2 r;
    unsigned lo = v << 16;
    unsigned hi = v & 0xFFFF0000u;
    r.x = __builtin_bit_cast(float, lo);
    r.y = __builtin_bit_cast(float, hi);
    return r;
}

// ---- fp8 e4m3 (OCP, gfx950 HW converts) ----
__device__ __forceinline__ unsigned char f2fp8(float f) {
    return (unsigned char)(__builtin_amdgcn_cvt_pk_fp8_f32(f, f, 0, false) & 0xFF);
}

// ---------------- init: pooled=0 ----------------
__global__ __launch_bounds__(256) void k_init(float* __restrict__ pooled) {
    int i = blockIdx.x * 256 + threadIdx.x;
    if (i < N_GRAPHS * HID) pooled[i] = 0.f;
}

// ---------------- per-block bucket histogram (LDS only, NO global atomics) ----------------
__global__ __launch_bounds__(256) void k_hist(const int* __restrict__ dst,
                                              int* __restrict__ cntm) {
    __shared__ int hist[NBUCK];
    int t = threadIdx.x;
    for (int i = t; i < NBUCK; i += 256) hist[i] = 0;
    __syncthreads();
    int base = blockIdx.x * EPB;
#pragma unroll
    for (int i = 0; i < (EPB + 255) / 256; ++i) {
        int e = i * 256 + t;
        if (e < EPB) atomicAdd(&hist[dst[base + e] >> 9], 1);
    }
    __syncthreads();
    for (int b = t; b < NBUCK; b += 256)
        cntm[b * NBF + blockIdx.x] = hist[b];
}

// ---------------- bucket totals: reduce each cntm row ----------------
__global__ __launch_bounds__(256) void k_btot(const int* __restrict__ cntm,
                                              int* __restrict__ tot) {
    __shared__ int red[256];
    int b = blockIdx.x, t = threadIdx.x;
    red[t] = cntm[b * NBF + t] + cntm[b * NBF + t + 256];
    __syncthreads();
    for (int off = 128; off > 0; off >>= 1) {
        if (t < off) red[t] += red[t + off];
        __syncthreads();
    }
    if (t == 0) tot[b] = red[0];
}

// ---------------- scan 196 bucket totals -> bbase; rowptr[N]=E ----------------
__global__ __launch_bounds__(256) void k_bscan(const int* __restrict__ tot,
                                               int* __restrict__ bbase,
                                               int* __restrict__ rowptr) {
    __shared__ int arr[256];
    int t = threadIdx.x;
    arr[t] = (t < NBUCK) ? tot[t] : 0;
    __syncthreads();
    for (int off = 1; off < 256; off <<= 1) {
        int v = (t >= off) ? arr[t - off] : 0;
        __syncthreads();
        arr[t] += v;
        __syncthreads();
    }
    if (t < NBUCK) bbase[t] = (t == 0) ? 0 : arr[t - 1];
    if (t == 0) rowptr[N_NODES] = N_EDGES;
}

// ---------------- per-(bucket,block) partition offsets ----------------
__global__ __launch_bounds__(NBF) void k_offs(const int* __restrict__ cntm,
                                              const int* __restrict__ bbase,
                                              int* __restrict__ offs) {
    __shared__ int arr[NBF];
    int b = blockIdx.x, t = threadIdx.x;
    arr[t] = cntm[b * NBF + t];
    __syncthreads();
    for (int off = 1; off < NBF; off <<= 1) {
        int v = (t >= off) ? arr[t - off] : 0;
        __syncthreads();
        arr[t] += v;
        __syncthreads();
    }
    offs[b * NBF + t] = bbase[b] + ((t == 0) ? 0 : arr[t - 1]);
}

// ---------------- partition: edges -> staging, grouped by 512-node bucket ----------------
// packed: (dst & 511) << 17 | src   (src < 2^17)
__global__ __launch_bounds__(256) void k_partition(const int* __restrict__ src,
                                                   const int* __restrict__ dst,
                                                   const int* __restrict__ offs,
                                                   unsigned* __restrict__ staging) {
    __shared__ int cur[NBUCK];
    int t = threadIdx.x;
    for (int b = t; b < NBUCK; b += 256) cur[b] = offs[b * NBF + blockIdx.x];
    __syncthreads();
    int base = blockIdx.x * EPB;
#pragma unroll
    for (int i = 0; i < (EPB + 255) / 256; ++i) {
        int e = i * 256 + t;
        if (e < EPB) {
            int d = dst[base + e];
            int s = src[base + e];
            int slot = atomicAdd(&cur[d >> 9], 1);
            staging[slot] = ((unsigned)(d & 511) << 17) | (unsigned)s;
        }
    }
}

// ---------------- fuse: per-bucket node histogram -> rowptr, dinv; then csr scatter ----------------
__global__ __launch_bounds__(256) void k_fuse(const unsigned* __restrict__ staging,
                                              const int* __restrict__ bbase,
                                              int* __restrict__ rowptr,
                                              float* __restrict__ dinv,
                                              int* __restrict__ csr_src) {
    __shared__ int cnt[512];
    __shared__ int cur[512];
    __shared__ int arr[256];
    int b = blockIdx.x, t = threadIdx.x;
    cnt[t] = 0; cnt[t + 256] = 0;
    __syncthreads();
    int beg = bbase[b];
    int end = (b == NBUCK - 1) ? N_EDGES : bbase[b + 1];
    for (int e = beg + t; e < end; e += 256)
        atomicAdd(&cnt[staging[e] >> 17], 1);
    __syncthreads();
    int c0 = cnt[2 * t], c1 = cnt[2 * t + 1];
    arr[t] = c0 + c1;
    __syncthreads();
    for (int off = 1; off < 256; off <<= 1) {
        int v = (t >= off) ? arr[t - off] : 0;
        __syncthreads();
        arr[t] += v;
        __syncthreads();
    }
    int excl = (t == 0) ? 0 : arr[t - 1];
    int p0 = beg + excl;
    int p1 = p0 + c0;
    cur[2 * t] = p0;
    cur[2 * t + 1] = p1;
    int n0 = b << 9;
    int n = n0 + 2 * t;
    if (n < N_NODES) { rowptr[n] = p0; dinv[n] = rsqrtf((float)(c0 + 1)); }
    n = n0 + 2 * t + 1;
    if (n < N_NODES) { rowptr[n] = p1; dinv[n] = rsqrtf((float)(c1 + 1)); }
    __syncthreads();
    for (int e = beg + t; e < end; e += 256) {
        unsigned v = staging[e];
        int pos = atomicAdd(&cur[v >> 17], 1);
        csr_src[pos] = (int)(v & 0x1FFFFu);
    }
}

// ---------------- W2 -> MFMA B-fragment layout, bf16 ----------------
__global__ __launch_bounds__(256) void k_w2pack(const float* __restrict__ W2,
                                                uint4* __restrict__ Bp) {
    int i = blockIdx.x * 256 + threadIdx.x;  // 2048 slots
    if (i >= 2048) return;
    int lane = i & 63;
    int kb = (i >> 6) & 3;
    int ct = i >> 8;
    int col = ct * 16 + (lane & 15);
    int k0 = kb * 32 + ((lane >> 4) & 3) * 8;
    unsigned w[4];
#pragma unroll
    for (int p = 0; p < 4; ++p) {
        int k = k0 + 2 * p;
        w[p] = packbf(W2[k * HID + col], W2[(k + 1) * HID + col]);
    }
    Bp[i] = make_uint4(w[0], w[1], w[2], w[3]);
}

// ---------------- prescale: xs[n][16] = bf16(x[n][ch] * dinv[n]), ch15 = 0 ----------------
__global__ __launch_bounds__(256) void k_prescale(const float* __restrict__ x,
                                                  const float* __restrict__ dinv,
                                                  unsigned* __restrict__ xs) {
    int i = blockIdx.x * 256 + threadIdx.x;  // one thread per (node, ch-pair)
    if (i >= N_NODES * 8) return;
    int n = i >> 3, p = i & 7;
    float dv = dinv[n];
    int c0 = 2 * p, c1 = c0 + 1;
    float a = x[(size_t)n * IN_CH + c0] * dv;                       // c0 <= 14 always
    float b = (c1 < IN_CH) ? x[(size_t)n * IN_CH + c1] * dv : 0.f;  // pad ch15
    xs[i] = packbf(a, b);
}

// ---------------- gather15: agg[n][16] = dinv[n]*(xs[n] + sum xs[src]) ----------------
__global__ __launch_bounds__(256) void k_gather15(const int* __restrict__ rowptr,
                                                  const int* __restrict__ csr_src,
                                                  const unsigned* __restrict__ xs,
                                                  const float* __restrict__ dinv,
                                                  float* __restrict__ agg) {
    int wave = (blockIdx.x * 256 + threadIdx.x) >> 6;
    if (wave >= N_NODES) return;
    int n = wave;
    int l = threadIdx.x & 63;
    unsigned g = (unsigned)(l >> 3), cp = (unsigned)(l & 7);
    int beg = rowptr[n], end = rowptr[n + 1];
    float2 acc = make_float2(0.f, 0.f);
    for (int e = beg + (int)g; e < end; e += 8) {
        unsigned s = (unsigned)csr_src[e];
        float2 v = unpackbf(xs[s * 8u + cp]);
        acc.x += v.x; acc.y += v.y;
    }
#pragma unroll
    for (int off = 8; off < 64; off <<= 1) {
        acc.x += __shfl_xor(acc.x, off, 64);
        acc.y += __shfl_xor(acc.y, off, 64);
    }
    if (l < 8) {
        float2 s = unpackbf(xs[(unsigned)n * 8u + (unsigned)l]);  // self term
        float dv = dinv[n];
        float2 r = make_float2((acc.x + s.x) * dv, (acc.y + s.y) * dv);
        *(float2*)&agg[(unsigned)n * 16u + 2u * (unsigned)l] = r;
    }
}

// ---------------- xform1b: h1 = bf16(relu(agg @ W1 + b1)) ----------------
// 25000 blocks, wave per node — massively parallel (fusion into xform2 regressed: r16)
__global__ __launch_bounds__(256) void k_xform1b(const float* __restrict__ agg,
                                                 const float* __restrict__ W1,
                                                 const float* __restrict__ b1,
                                                 unsigned* __restrict__ h1b) {
    __shared__ float w[IN_CH * HID];  // 7.5 KB
    int t = threadIdx.x;
    for (int i = t; i < IN_CH * HID; i += 256) w[i] = W1[i];
    __syncthreads();
    int node = blockIdx.x * 4 + (t >> 6);
    int lane = t & 63;
    int c = lane * 2;
    const float* ar = agg + (size_t)node * 16;
    float a0 = b1[c], a1 = b1[c + 1];
#pragma unroll
    for (int k = 0; k < IN_CH; ++k) {
        float av = ar[k];
        a0 += av * w[k * HID + c];
        a1 += av * w[k * HID + c + 1];
    }
    h1b[(size_t)node * 64 + lane] = packbf(fmaxf(a0, 0.f), fmaxf(a1, 0.f));
}

// ---------------- layer-2 transform via MFMA: m = fp8e4m3((h1 @ W2) * dinv), row-major [n][128] ----------------
__global__ __launch_bounds__(256) void k_xform2(const unsigned* __restrict__ h1b,
                                                const uint4* __restrict__ Bp,
                                                const float* __restrict__ dinv,
                                                unsigned char* __restrict__ mout) {
    int lane = threadIdx.x & 63;
    int wid = threadIdx.x >> 6;
    int row0 = blockIdx.x * 64 + wid * 16;
    int arow = row0 + (lane & 15);
    const uint4* hbase = (const uint4*)h1b;
    uint4 a_u[4];
#pragma unroll
    for (int kb = 0; kb < 4; ++kb)
        a_u[kb] = hbase[(size_t)arow * 16 + kb * 4 + (lane >> 4)];
    int rbase = row0 + (lane >> 4) * 4;
    float dv[4];
#pragma unroll
    for (int j = 0; j < 4; ++j) dv[j] = dinv[min(rbase + j, N_NODES - 1)];
#pragma unroll
    for (int ct = 0; ct < 8; ++ct) {
        f32x4 acc = {0.f, 0.f, 0.f, 0.f};
#pragma unroll
        for (int kb = 0; kb < 4; ++kb) {
            uint4 b_u = Bp[(ct * 4 + kb) * 64 + lane];
            acc = __builtin_amdgcn_mfma_f32_16x16x32_bf16(
                __builtin_bit_cast(short8, a_u[kb]),
                __builtin_bit_cast(short8, b_u), acc, 0, 0, 0);
        }
        int col = ct * 16 + (lane & 15);
#pragma unroll
        for (int j = 0; j < 4; ++j) {
            int r = rbase + j;
            if (r < N_NODES) mout[(size_t)r * HID + col] = f2fp8(acc[j] * dv[j]);
        }
    }
}

// ---------------- gather (layer 2): out = bf16(relu(dinv*(m[n]+sum m[src])+b)) ----------------
// one wave per node; 32 lanes per 128B fp8 row (lane owns 4 channels via uint load);
// wave halves process even/odd edges -> half the load+decode instructions at same bytes/MLP.
__global__ __launch_bounds__(256) void k_gather(const int* __restrict__ rowptr,
                                                const int* __restrict__ csr_src,
                                                const unsigned* __restrict__ m,
                                                const float* __restrict__ bias,
                                                const float* __restrict__ dinv,
                                                unsigned* __restrict__ outh) {
    int wave = (blockIdx.x * 256 + threadIdx.x) >> 6;
    if (wave >= N_NODES) return;
    unsigned n = (unsigned)wave;
    int lane = threadIdx.x & 63;
    int half = lane >> 5;
    unsigned li = (unsigned)(lane & 31);
    int beg = rowptr[n], end = rowptr[n + 1];
    f32x4 acc = {0.f, 0.f, 0.f, 0.f};
    if (half == 0) {  // self-loop term once
        unsigned u = m[n * 32u + li];
        f32x2 lo = __builtin_amdgcn_cvt_pk_f32_fp8((int)u, false);
        f32x2 hi = __builtin_amdgcn_cvt_pk_f32_fp8((int)u, true);
        acc[0] += lo[0]; acc[1] += lo[1]; acc[2] += hi[0]; acc[3] += hi[1];
    }
    int e = beg + half;
    for (; e + 6 < end; e += 8) {  // 4 edges per half in flight (8 per wave)
        unsigned o0 = (unsigned)csr_src[e + 0] * 32u + li;
        unsigned o1 = (unsigned)csr_src[e + 2] * 32u + li;
        unsigned o2 = (unsigned)csr_src[e + 4] * 32u + li;
        unsigned o3 = (unsigned)csr_src[e + 6] * 32u + li;
        unsigned u0 = m[o0];
        unsigned u1 = m[o1];
        unsigned u2 = m[o2];
        unsigned u3 = m[o3];
        f32x2 l0 = __builtin_amdgcn_cvt_pk_f32_fp8((int)u0, false);
        f32x2 h0 = __builtin_amdgcn_cvt_pk_f32_fp8((int)u0, true);
        f32x2 l1 = __builtin_amdgcn_cvt_pk_f32_fp8((int)u1, false);
        f32x2 h1 = __builtin_amdgcn_cvt_pk_f32_fp8((int)u1, true);
        f32x2 l2 = __builtin_amdgcn_cvt_pk_f32_fp8((int)u2, false);
        f32x2 h2 = __builtin_amdgcn_cvt_pk_f32_fp8((int)u2, true);
        f32x2 l3 = __builtin_amdgcn_cvt_pk_f32_fp8((int)u3, false);
        f32x2 h3 = __builtin_amdgcn_cvt_pk_f32_fp8((int)u3, true);
        acc[0] += l0[0] + l1[0] + l2[0] + l3[0];
        acc[1] += l0[1] + l1[1] + l2[1] + l3[1];
        acc[2] += h0[0] + h1[0] + h2[0] + h3[0];
        acc[3] += h0[1] + h1[1] + h2[1] + h3[1];
    }
    for (; e < end; e += 2) {
        unsigned u = m[(unsigned)csr_src[e] * 32u + li];
        f32x2 lo = __builtin_amdgcn_cvt_pk_f32_fp8((int)u, false);
        f32x2 hi = __builtin_amdgcn_cvt_pk_f32_fp8((int)u, true);
        acc[0] += lo[0]; acc[1] += lo[1]; acc[2] += hi[0]; acc[3] += hi[1];
    }
    // cross-half reduce (even-edge half + odd-edge half)
#pragma unroll
    for (int j = 0; j < 4; ++j) acc[j] += __shfl_xor(acc[j], 32, 64);
    if (half == 0) {
        float dv = dinv[n];
        float4 b = *(const float4*)&bias[li * 4u];
        float r0 = fmaxf(acc[0] * dv + b.x, 0.f);
        float r1 = fmaxf(acc[1] * dv + b.y, 0.f);
        float r2 = fmaxf(acc[2] * dv + b.z, 0.f);
        float r3 = fmaxf(acc[3] * dv + b.w, 0.f);
        uint2 ov;
        ov.x = packbf(r0, r1);
        ov.y = packbf(r2, r3);
        *(uint2*)&outh[n * 64u + li * 2u] = ov;
    }
}

// ---------------- node count per graph: binary search on sorted batch ----------------
__global__ __launch_bounds__(64) void k_cnt(const int* __restrict__ batch,
                                            int* __restrict__ cnt) {
    int g = threadIdx.x;
    if (g >= N_GRAPHS) return;
    int lo0 = 0, hi0 = N_NODES;
    while (lo0 < hi0) { int mid = (lo0 + hi0) >> 1; if (batch[mid] < g) lo0 = mid + 1; else hi0 = mid; }
    int lo1 = lo0, hi1 = N_NODES;
    while (lo1 < hi1) { int mid = (lo1 + hi1) >> 1; if (batch[mid] < g + 1) lo1 = mid + 1; else hi1 = mid; }
    cnt[g] = lo1 - lo0;
}

// ---------------- pooled sums over packed bf16 h2 ----------------
#define POOL_CHUNK 128
__global__ __launch_bounds__(256) void k_pool(const unsigned* __restrict__ h,
                                              const int* __restrict__ batch,
                                              float* __restrict__ pooled) {
    int t = threadIdx.x;
    int lane = t & 63;
    int grp = t >> 6;  // 0..3
    int start = blockIdx.x * POOL_CHUNK;
    int end = min(start + POOL_CHUNK, N_NODES);
    float2 acc = make_float2(0.f, 0.f);
    int cur = -1;
    for (int n = start + grp; n < end; n += 4) {
        int g = batch[n];
        if (g != cur) {
            if (cur >= 0) {
                atomicAdd(&pooled[cur * HID + lane * 2], acc.x);
                atomicAdd(&pooled[cur * HID + lane * 2 + 1], acc.y);
            }
            acc = make_float2(0.f, 0.f);
            cur = g;
        }
        float2 v = unpackbf(h[(unsigned)n * 64u + (unsigned)lane]);
        acc.x += v.x; acc.y += v.y;
    }
    if (cur >= 0) {
        atomicAdd(&pooled[cur * HID + lane * 2], acc.x);
        atomicAdd(&pooled[cur * HID + lane * 2 + 1], acc.y);
    }
}

// ---------------- final: out = (pooled/cnt) @ Wf + bf ----------------
__global__ __launch_bounds__(128) void k_final(const float* __restrict__ pooled,
                                               const int* __restrict__ cnt,
                                               const float* __restrict__ Wf,
                                               const float* __restrict__ bf,
                                               float* __restrict__ out) {
    __shared__ float p[HID];
    int g = blockIdx.x, t = threadIdx.x;
    float inv = 1.f / fmaxf((float)cnt[g], 1.f);
    p[t] = pooled[g * HID + t] * inv;
    __syncthreads();
    if (t < NCLS) {
        float acc = bf[t];
        for (int k = 0; k < HID; ++k) acc += p[k] * Wf[k * NCLS + t];
        out[g * NCLS + t] = acc;
    }
}

extern "C" void kernel_launch(void* const* d_in, const int* in_sizes, int n_in,
                              void* d_out, int out_size, void* d_ws, size_t ws_size,
                              hipStream_t stream) {
    const float* x   = (const float*)d_in[0];
    const int*   ei  = (const int*)d_in[1];   // [2][E] flat
    const int*   src = ei;
    const int*   dst = ei + N_EDGES;
    const int*   batch = (const int*)d_in[2];
    const float* W1 = (const float*)d_in[3];
    const float* b1 = (const float*)d_in[4];
    const float* W2 = (const float*)d_in[5];
    const float* b2 = (const float*)d_in[6];
    const float* Wf = (const float*)d_in[7];
    const float* bf = (const float*)d_in[8];
    float* out = (float*)d_out;

    char* ws = (char*)d_ws;
    size_t off = 0;
    unsigned* mbuf = (unsigned*)(ws + off);  off += (size_t)N_NODES * 64 * 4;   // 25.6 MB: xs+agg early, fp8 messages late
    unsigned* h1b = (unsigned*)(ws + off);   off += (size_t)N_NODES * 64 * 4;   // 25.6 MB bf16 h1
    unsigned* h2b = (unsigned*)(ws + off);   off += (size_t)N_NODES * 64 * 4;   // 25.6 MB bf16 h2 / staging
    int* csr_src = (int*)(ws + off);         off += (size_t)N_EDGES * 4;        // 6.4 MB
    uint4* Bp = (uint4*)(ws + off);          off += (size_t)2048 * 16;          // 32 KB
    float* dinv = (float*)(ws + off);        off += (size_t)N_NODES * 4;
    int* rowptr = (int*)(ws + off);          off += (size_t)(N_NODES + 1) * 4;
    int* cntm = (int*)(ws + off);            off += (size_t)NBUCK * NBF * 4;    // 400 KB
    int* offs = (int*)(ws + off);            off += (size_t)NBUCK * NBF * 4;    // 400 KB
    int* tot = (int*)(ws + off);             off += (size_t)NBUCK * 4;
    int* bbase = (int*)(ws + off);           off += (size_t)NBUCK * 4;
    float* pooled = (float*)(ws + off);      off += (size_t)N_GRAPHS * HID * 4;
    int* cnt = (int*)(ws + off);             off += (size_t)N_GRAPHS * 4;
    // aliases: staging lives in h2b (dead until gather2 writes h2);
    // xs (3.2 MB) + agg (6.4 MB) live in mbuf; fp8 messages overwrite mbuf after agg is dead
    unsigned* staging = h2b;
    unsigned* xs = mbuf;
    float* agg = (float*)(mbuf + (size_t)N_NODES * 8);
    unsigned char* mfp8 = (unsigned char*)mbuf;

    // graph preprocessing (zero global atomics)
    k_init<<<(N_GRAPHS * HID + 255) / 256, 256, 0, stream>>>(pooled);
    k_hist<<<NBF, 256, 0, stream>>>(dst, cntm);
    k_btot<<<NBUCK, 256, 0, stream>>>(cntm, tot);
    k_bscan<<<1, 256, 0, stream>>>(tot, bbase, rowptr);
    k_offs<<<NBUCK, NBF, 0, stream>>>(cntm, bbase, offs);
    k_partition<<<NBF, 256, 0, stream>>>(src, dst, offs, staging);
    k_fuse<<<NBUCK, 256, 0, stream>>>(staging, bbase, rowptr, dinv, csr_src);
    k_w2pack<<<8, 256, 0, stream>>>(W2, Bp);

    // layer 1: aggregate-first (15-ch rows)
    k_prescale<<<(N_NODES * 8 + 255) / 256, 256, 0, stream>>>(x, dinv, xs);
    k_gather15<<<(N_NODES + 3) / 4, 256, 0, stream>>>(rowptr, csr_src, xs, dinv, agg);
    k_xform1b<<<N_NODES / 4, 256, 0, stream>>>(agg, W1, b1, h1b);

    // layer 2: MFMA transform (reads h1b, writes fp8 into mbuf; agg dead) + fp8 gather
    k_xform2<<<(N_NODES + 63) / 64, 256, 0, stream>>>(h1b, Bp, dinv, mfp8);
    k_gather<<<(N_NODES + 3) / 4, 256, 0, stream>>>(rowptr, csr_src, (const unsigned*)mfp8, b2, dinv, h2b);

    // pooling + classifier
    k_cnt<<<1, 64, 0, stream>>>(batch, cnt);
    k_pool<<<(N_NODES + POOL_CHUNK - 1) / POOL_CHUNK, 256, 0, stream>>>(h2b, batch, pooled);
    k_final<<<N_GRAPHS, 128, 0, stream>>>(pooled, cnt, Wf, bf, out);
}

// Round 18
// 223.343 us; speedup vs baseline: 1.0525x; 1.0525x over previous
//
#include <hip/hip_runtime.h>

#define N_NODES 100000
#define N_EDGES 1600000
#define N_GRAPHS 64
#define IN_CH 15
#define HID 128
#define NCLS 11

// bucketed CSR geometry
#define NBUCK 196            // ceil(100000 / 512), bucket = dst >> 9
#define NBF 512              // partition blocks
#define EPB (N_EDGES / NBF)  // 3125 edges per block

using short8 = __attribute__((ext_vector_type(8))) short;
using f32x4 = __attribute__((ext_vector_type(4))) float;
using f32x2 = __attribute__((ext_vector_type(2))) float;

// ---- bf16 pack/unpack (RNE) ----
__device__ __forceinline__ unsigned short f2bf(float f) {
    unsigned u = __builtin_bit_cast(unsigned, f);
    u += 0x7FFF + ((u >> 16) & 1);
    return (unsigned short)(u >> 16);
}
__device__ __forceinline__ unsigned packbf(float a, float b) {
    return (unsigned)f2bf(a) | ((unsigned)f2bf(b) << 16);
}
__device__ __forceinline__ float2 unpackbf(unsigned v) {
    float2 r;
    unsigned lo = v << 16;
    unsigned hi = v & 0xFFFF0000u;
    r.x = __builtin_bit_cast(float, lo);
    r.y = __builtin_bit_cast(float, hi);
    return r;
}

// ---- fp8 e4m3 (OCP, gfx950 HW converts) ----
__device__ __forceinline__ unsigned char f2fp8(float f) {
    return (unsigned char)(__builtin_amdgcn_cvt_pk_fp8_f32(f, f, 0, false) & 0xFF);
}

// ---------------- init: pooled=0 ----------------
__global__ __launch_bounds__(256) void k_init(float* __restrict__ pooled) {
    int i = blockIdx.x * 256 + threadIdx.x;
    if (i < N_GRAPHS * HID) pooled[i] = 0.f;
}

// ---------------- per-block bucket histogram (LDS only, NO global atomics) ----------------
__global__ __launch_bounds__(256) void k_hist(const int* __restrict__ dst,
                                              int* __restrict__ cntm) {
    __shared__ int hist[NBUCK];
    int t = threadIdx.x;
    for (int i = t; i < NBUCK; i += 256) hist[i] = 0;
    __syncthreads();
    int base = blockIdx.x * EPB;
#pragma unroll
    for (int i = 0; i < (EPB + 255) / 256; ++i) {
        int e = i * 256 + t;
        if (e < EPB) atomicAdd(&hist[dst[base + e] >> 9], 1);
    }
    __syncthreads();
    for (int b = t; b < NBUCK; b += 256)
        cntm[b * NBF + blockIdx.x] = hist[b];
}

// ---------------- bucket totals: reduce each cntm row ----------------
__global__ __launch_bounds__(256) void k_btot(const int* __restrict__ cntm,
                                              int* __restrict__ tot) {
    __shared__ int red[256];
    int b = blockIdx.x, t = threadIdx.x;
    red[t] = cntm[b * NBF + t] + cntm[b * NBF + t + 256];
    __syncthreads();
    for (int off = 128; off > 0; off >>= 1) {
        if (t < off) red[t] += red[t + off];
        __syncthreads();
    }
    if (t == 0) tot[b] = red[0];
}

// ---------------- scan 196 bucket totals -> bbase; rowptr[N]=E ----------------
__global__ __launch_bounds__(256) void k_bscan(const int* __restrict__ tot,
                                               int* __restrict__ bbase,
                                               int* __restrict__ rowptr) {
    __shared__ int arr[256];
    int t = threadIdx.x;
    arr[t] = (t < NBUCK) ? tot[t] : 0;
    __syncthreads();
    for (int off = 1; off < 256; off <<= 1) {
        int v = (t >= off) ? arr[t - off] : 0;
        __syncthreads();
        arr[t] += v;
        __syncthreads();
    }
    if (t < NBUCK) bbase[t] = (t == 0) ? 0 : arr[t - 1];
    if (t == 0) rowptr[N_NODES] = N_EDGES;
}

// ---------------- per-(bucket,block) partition offsets ----------------
__global__ __launch_bounds__(NBF) void k_offs(const int* __restrict__ cntm,
                                              const int* __restrict__ bbase,
                                              int* __restrict__ offs) {
    __shared__ int arr[NBF];
    int b = blockIdx.x, t = threadIdx.x;
    arr[t] = cntm[b * NBF + t];
    __syncthreads();
    for (int off = 1; off < NBF; off <<= 1) {
        int v = (t >= off) ? arr[t - off] : 0;
        __syncthreads();
        arr[t] += v;
        __syncthreads();
    }
    offs[b * NBF + t] = bbase[b] + ((t == 0) ? 0 : arr[t - 1]);
}

// ---------------- partition: edges -> staging, grouped by 512-node bucket ----------------
// packed: (dst & 511) << 17 | src   (src < 2^17)
__global__ __launch_bounds__(256) void k_partition(const int* __restrict__ src,
                                                   const int* __restrict__ dst,
                                                   const int* __restrict__ offs,
                                                   unsigned* __restrict__ staging) {
    __shared__ int cur[NBUCK];
    int t = threadIdx.x;
    for (int b = t; b < NBUCK; b += 256) cur[b] = offs[b * NBF + blockIdx.x];
    __syncthreads();
    int base = blockIdx.x * EPB;
#pragma unroll
    for (int i = 0; i < (EPB + 255) / 256; ++i) {
        int e = i * 256 + t;
        if (e < EPB) {
            int d = dst[base + e];
            int s = src[base + e];
            int slot = atomicAdd(&cur[d >> 9], 1);
            staging[slot] = ((unsigned)(d & 511) << 17) | (unsigned)s;
        }
    }
}

// ---------------- fuse: per-bucket node histogram -> rowptr, dinv; then csr scatter ----------------
__global__ __launch_bounds__(256) void k_fuse(const unsigned* __restrict__ staging,
                                              const int* __restrict__ bbase,
                                              int* __restrict__ rowptr,
                                              float* __restrict__ dinv,
                                              int* __restrict__ csr_src) {
    __shared__ int cnt[512];
    __shared__ int cur[512];
    __shared__ int arr[256];
    int b = blockIdx.x, t = threadIdx.x;
    cnt[t] = 0; cnt[t + 256] = 0;
    __syncthreads();
    int beg = bbase[b];
    int end = (b == NBUCK - 1) ? N_EDGES : bbase[b + 1];
    for (int e = beg + t; e < end; e += 256)
        atomicAdd(&cnt[staging[e] >> 17], 1);
    __syncthreads();
    int c0 = cnt[2 * t], c1 = cnt[2 * t + 1];
    arr[t] = c0 + c1;
    __syncthreads();
    for (int off = 1; off < 256; off <<= 1) {
        int v = (t >= off) ? arr[t - off] : 0;
        __syncthreads();
        arr[t] += v;
        __syncthreads();
    }
    int excl = (t == 0) ? 0 : arr[t - 1];
    int p0 = beg + excl;
    int p1 = p0 + c0;
    cur[2 * t] = p0;
    cur[2 * t + 1] = p1;
    int n0 = b << 9;
    int n = n0 + 2 * t;
    if (n < N_NODES) { rowptr[n] = p0; dinv[n] = rsqrtf((float)(c0 + 1)); }
    n = n0 + 2 * t + 1;
    if (n < N_NODES) { rowptr[n] = p1; dinv[n] = rsqrtf((float)(c1 + 1)); }
    __syncthreads();
    for (int e = beg + t; e < end; e += 256) {
        unsigned v = staging[e];
        int pos = atomicAdd(&cur[v >> 17], 1);
        csr_src[pos] = (int)(v & 0x1FFFFu);
    }
}

// ---------------- W2 -> MFMA B-fragment layout, bf16 ----------------
__global__ __launch_bounds__(256) void k_w2pack(const float* __restrict__ W2,
                                                uint4* __restrict__ Bp) {
    int i = blockIdx.x * 256 + threadIdx.x;  // 2048 slots
    if (i >= 2048) return;
    int lane = i & 63;
    int kb = (i >> 6) & 3;
    int ct = i >> 8;
    int col = ct * 16 + (lane & 15);
    int k0 = kb * 32 + ((lane >> 4) & 3) * 8;
    unsigned w[4];
#pragma unroll
    for (int p = 0; p < 4; ++p) {
        int k = k0 + 2 * p;
        w[p] = packbf(W2[k * HID + col], W2[(k + 1) * HID + col]);
    }
    Bp[i] = make_uint4(w[0], w[1], w[2], w[3]);
}

// ---------------- prescale: xs[n][16] = bf16(x[n][ch] * dinv[n]), ch15 = 0 ----------------
__global__ __launch_bounds__(256) void k_prescale(const float* __restrict__ x,
                                                  const float* __restrict__ dinv,
                                                  unsigned* __restrict__ xs) {
    int i = blockIdx.x * 256 + threadIdx.x;  // one thread per (node, ch-pair)
    if (i >= N_NODES * 8) return;
    int n = i >> 3, p = i & 7;
    float dv = dinv[n];
    int c0 = 2 * p, c1 = c0 + 1;
    float a = x[(size_t)n * IN_CH + c0] * dv;                       // c0 <= 14 always
    float b = (c1 < IN_CH) ? x[(size_t)n * IN_CH + c1] * dv : 0.f;  // pad ch15
    xs[i] = packbf(a, b);
}

// ---------------- gather15: agg[n][16] = dinv[n]*(xs[n] + sum xs[src]) ----------------
__global__ __launch_bounds__(256) void k_gather15(const int* __restrict__ rowptr,
                                                  const int* __restrict__ csr_src,
                                                  const unsigned* __restrict__ xs,
                                                  const float* __restrict__ dinv,
                                                  float* __restrict__ agg) {
    int wave = (blockIdx.x * 256 + threadIdx.x) >> 6;
    if (wave >= N_NODES) return;
    int n = wave;
    int l = threadIdx.x & 63;
    unsigned g = (unsigned)(l >> 3), cp = (unsigned)(l & 7);
    int beg = rowptr[n], end = rowptr[n + 1];
    float2 acc = make_float2(0.f, 0.f);
    for (int e = beg + (int)g; e < end; e += 8) {
        unsigned s = (unsigned)csr_src[e];
        float2 v = unpackbf(xs[s * 8u + cp]);
        acc.x += v.x; acc.y += v.y;
    }
#pragma unroll
    for (int off = 8; off < 64; off <<= 1) {
        acc.x += __shfl_xor(acc.x, off, 64);
        acc.y += __shfl_xor(acc.y, off, 64);
    }
    if (l < 8) {
        float2 s = unpackbf(xs[(unsigned)n * 8u + (unsigned)l]);  // self term
        float dv = dinv[n];
        float2 r = make_float2((acc.x + s.x) * dv, (acc.y + s.y) * dv);
        *(float2*)&agg[(unsigned)n * 16u + 2u * (unsigned)l] = r;
    }
}

// ---------------- xform1c: h1 = bf16(relu(agg @ W1 + b1)), W1 in registers ----------------
// Lane owns columns (2l, 2l+1): 15 coalesced float2 W1 loads once per wave (no LDS, no sync);
// wave processes 8 nodes (agg reads wave-uniform broadcasts; stores coalesced 256B).
// Replaces xform1b whose 25000-block LDS staging of W1 cost ~187MB aggregate L2 reads.
__global__ __launch_bounds__(256) void k_xform1c(const float* __restrict__ agg,
                                                 const float* __restrict__ W1,
                                                 const float* __restrict__ b1,
                                                 unsigned* __restrict__ h1b) {
    int t = threadIdx.x;
    int lane = t & 63;
    int wid = t >> 6;
    int c = lane * 2;
    float2 w[IN_CH];
#pragma unroll
    for (int k = 0; k < IN_CH; ++k) w[k] = *(const float2*)&W1[k * HID + c];
    float2 bb = *(const float2*)&b1[c];
    int n0 = blockIdx.x * 32 + wid * 8;  // 100000 = 3125 * 32
#pragma unroll
    for (int j = 0; j < 8; ++j) {
        int node = n0 + j;
        const float* ar = agg + (size_t)node * 16;
        float a0 = bb.x, a1 = bb.y;
#pragma unroll
        for (int k = 0; k < IN_CH; ++k) {
            float av = ar[k];
            a0 += av * w[k].x;
            a1 += av * w[k].y;
        }
        h1b[(size_t)node * 64 + lane] = packbf(fmaxf(a0, 0.f), fmaxf(a1, 0.f));
    }
}

// ---------------- layer-2 transform via MFMA: m = fp8e4m3((h1 @ W2) * dinv), row-major [n][128] ----------------
__global__ __launch_bounds__(256) void k_xform2(const unsigned* __restrict__ h1b,
                                                const uint4* __restrict__ Bp,
                                                const float* __restrict__ dinv,
                                                unsigned char* __restrict__ mout) {
    int lane = threadIdx.x & 63;
    int wid = threadIdx.x >> 6;
    int row0 = blockIdx.x * 64 + wid * 16;
    int arow = row0 + (lane & 15);
    const uint4* hbase = (const uint4*)h1b;
    uint4 a_u[4];
#pragma unroll
    for (int kb = 0; kb < 4; ++kb)
        a_u[kb] = hbase[(size_t)arow * 16 + kb * 4 + (lane >> 4)];
    int rbase = row0 + (lane >> 4) * 4;
    float dv[4];
#pragma unroll
    for (int j = 0; j < 4; ++j) dv[j] = dinv[min(rbase + j, N_NODES - 1)];
#pragma unroll
    for (int ct = 0; ct < 8; ++ct) {
        f32x4 acc = {0.f, 0.f, 0.f, 0.f};
#pragma unroll
        for (int kb = 0; kb < 4; ++kb) {
            uint4 b_u = Bp[(ct * 4 + kb) * 64 + lane];
            acc = __builtin_amdgcn_mfma_f32_16x16x32_bf16(
                __builtin_bit_cast(short8, a_u[kb]),
                __builtin_bit_cast(short8, b_u), acc, 0, 0, 0);
        }
        int col = ct * 16 + (lane & 15);
#pragma unroll
        for (int j = 0; j < 4; ++j) {
            int r = rbase + j;
            if (r < N_NODES) mout[(size_t)r * HID + col] = f2fp8(acc[j] * dv[j]);
        }
    }
}

// ---------------- gather (layer 2): out = bf16(relu(dinv*(m[n]+sum m[src])+b)) ----------------
// one wave per node; 32 lanes per 128B fp8 row (lane owns 4 channels via uint load);
// wave halves process even/odd edges. At random-access service floor (~55us) — do not touch.
__global__ __launch_bounds__(256) void k_gather(const int* __restrict__ rowptr,
                                                const int* __restrict__ csr_src,
                                                const unsigned* __restrict__ m,
                                                const float* __restrict__ bias,
                                                const float* __restrict__ dinv,
                                                unsigned* __restrict__ outh) {
    int wave = (blockIdx.x * 256 + threadIdx.x) >> 6;
    if (wave >= N_NODES) return;
    unsigned n = (unsigned)wave;
    int lane = threadIdx.x & 63;
    int half = lane >> 5;
    unsigned li = (unsigned)(lane & 31);
    int beg = rowptr[n], end = rowptr[n + 1];
    f32x4 acc = {0.f, 0.f, 0.f, 0.f};
    if (half == 0) {  // self-loop term once
        unsigned u = m[n * 32u + li];
        f32x2 lo = __builtin_amdgcn_cvt_pk_f32_fp8((int)u, false);
        f32x2 hi = __builtin_amdgcn_cvt_pk_f32_fp8((int)u, true);
        acc[0] += lo[0]; acc[1] += lo[1]; acc[2] += hi[0]; acc[3] += hi[1];
    }
    int e = beg + half;
    for (; e + 6 < end; e += 8) {  // 4 edges per half in flight (8 per wave)
        unsigned o0 = (unsigned)csr_src[e + 0] * 32u + li;
        unsigned o1 = (unsigned)csr_src[e + 2] * 32u + li;
        unsigned o2 = (unsigned)csr_src[e + 4] * 32u + li;
        unsigned o3 = (unsigned)csr_src[e + 6] * 32u + li;
        unsigned u0 = m[o0];
        unsigned u1 = m[o1];
        unsigned u2 = m[o2];
        unsigned u3 = m[o3];
        f32x2 l0 = __builtin_amdgcn_cvt_pk_f32_fp8((int)u0, false);
        f32x2 h0 = __builtin_amdgcn_cvt_pk_f32_fp8((int)u0, true);
        f32x2 l1 = __builtin_amdgcn_cvt_pk_f32_fp8((int)u1, false);
        f32x2 h1 = __builtin_amdgcn_cvt_pk_f32_fp8((int)u1, true);
        f32x2 l2 = __builtin_amdgcn_cvt_pk_f32_fp8((int)u2, false);
        f32x2 h2 = __builtin_amdgcn_cvt_pk_f32_fp8((int)u2, true);
        f32x2 l3 = __builtin_amdgcn_cvt_pk_f32_fp8((int)u3, false);
        f32x2 h3 = __builtin_amdgcn_cvt_pk_f32_fp8((int)u3, true);
        acc[0] += l0[0] + l1[0] + l2[0] + l3[0];
        acc[1] += l0[1] + l1[1] + l2[1] + l3[1];
        acc[2] += h0[0] + h1[0] + h2[0] + h3[0];
        acc[3] += h0[1] + h1[1] + h2[1] + h3[1];
    }
    for (; e < end; e += 2) {
        unsigned u = m[(unsigned)csr_src[e] * 32u + li];
        f32x2 lo = __builtin_amdgcn_cvt_pk_f32_fp8((int)u, false);
        f32x2 hi = __builtin_amdgcn_cvt_pk_f32_fp8((int)u, true);
        acc[0] += lo[0]; acc[1] += lo[1]; acc[2] += hi[0]; acc[3] += hi[1];
    }
    // cross-half reduce (even-edge half + odd-edge half)
#pragma unroll
    for (int j = 0; j < 4; ++j) acc[j] += __shfl_xor(acc[j], 32, 64);
    if (half == 0) {
        float dv = dinv[n];
        float4 b = *(const float4*)&bias[li * 4u];
        float r0 = fmaxf(acc[0] * dv + b.x, 0.f);
        float r1 = fmaxf(acc[1] * dv + b.y, 0.f);
        float r2 = fmaxf(acc[2] * dv + b.z, 0.f);
        float r3 = fmaxf(acc[3] * dv + b.w, 0.f);
        uint2 ov;
        ov.x = packbf(r0, r1);
        ov.y = packbf(r2, r3);
        *(uint2*)&outh[n * 64u + li * 2u] = ov;
    }
}

// ---------------- node count per graph: binary search on sorted batch ----------------
__global__ __launch_bounds__(64) void k_cnt(const int* __restrict__ batch,
                                            int* __restrict__ cnt) {
    int g = threadIdx.x;
    if (g >= N_GRAPHS) return;
    int lo0 = 0, hi0 = N_NODES;
    while (lo0 < hi0) { int mid = (lo0 + hi0) >> 1; if (batch[mid] < g) lo0 = mid + 1; else hi0 = mid; }
    int lo1 = lo0, hi1 = N_NODES;
    while (lo1 < hi1) { int mid = (lo1 + hi1) >> 1; if (batch[mid] < g + 1) lo1 = mid + 1; else hi1 = mid; }
    cnt[g] = lo1 - lo0;
}

// ---------------- pooled sums over packed bf16 h2 ----------------
#define POOL_CHUNK 128
__global__ __launch_bounds__(256) void k_pool(const unsigned* __restrict__ h,
                                              const int* __restrict__ batch,
                                              float* __restrict__ pooled) {
    int t = threadIdx.x;
    int lane = t & 63;
    int grp = t >> 6;  // 0..3
    int start = blockIdx.x * POOL_CHUNK;
    int end = min(start + POOL_CHUNK, N_NODES);
    float2 acc = make_float2(0.f, 0.f);
    int cur = -1;
    for (int n = start + grp; n < end; n += 4) {
        int g = batch[n];
        if (g != cur) {
            if (cur >= 0) {
                atomicAdd(&pooled[cur * HID + lane * 2], acc.x);
                atomicAdd(&pooled[cur * HID + lane * 2 + 1], acc.y);
            }
            acc = make_float2(0.f, 0.f);
            cur = g;
        }
        float2 v = unpackbf(h[(unsigned)n * 64u + (unsigned)lane]);
        acc.x += v.x; acc.y += v.y;
    }
    if (cur >= 0) {
        atomicAdd(&pooled[cur * HID + lane * 2], acc.x);
        atomicAdd(&pooled[cur * HID + lane * 2 + 1], acc.y);
    }
}

// ---------------- final: out = (pooled/cnt) @ Wf + bf ----------------
__global__ __launch_bounds__(128) void k_final(const float* __restrict__ pooled,
                                               const int* __restrict__ cnt,
                                               const float* __restrict__ Wf,
                                               const float* __restrict__ bf,
                                               float* __restrict__ out) {
    __shared__ float p[HID];
    int g = blockIdx.x, t = threadIdx.x;
    float inv = 1.f / fmaxf((float)cnt[g], 1.f);
    p[t] = pooled[g * HID + t] * inv;
    __syncthreads();
    if (t < NCLS) {
        float acc = bf[t];
        for (int k = 0; k < HID; ++k) acc += p[k] * Wf[k * NCLS + t];
        out[g * NCLS + t] = acc;
    }
}

extern "C" void kernel_launch(void* const* d_in, const int* in_sizes, int n_in,
                              void* d_out, int out_size, void* d_ws, size_t ws_size,
                              hipStream_t stream) {
    const float* x   = (const float*)d_in[0];
    const int*   ei  = (const int*)d_in[1];   // [2][E] flat
    const int*   src = ei;
    const int*   dst = ei + N_EDGES;
    const int*   batch = (const int*)d_in[2];
    const float* W1 = (const float*)d_in[3];
    const float* b1 = (const float*)d_in[4];
    const float* W2 = (const float*)d_in[5];
    const float* b2 = (const float*)d_in[6];
    const float* Wf = (const float*)d_in[7];
    const float* bf = (const float*)d_in[8];
    float* out = (float*)d_out;

    char* ws = (char*)d_ws;
    size_t off = 0;
    unsigned* mbuf = (unsigned*)(ws + off);  off += (size_t)N_NODES * 64 * 4;   // 25.6 MB: xs+agg early, fp8 messages late
    unsigned* h1b = (unsigned*)(ws + off);   off += (size_t)N_NODES * 64 * 4;   // 25.6 MB bf16 h1
    unsigned* h2b = (unsigned*)(ws + off);   off += (size_t)N_NODES * 64 * 4;   // 25.6 MB bf16 h2 / staging
    int* csr_src = (int*)(ws + off);         off += (size_t)N_EDGES * 4;        // 6.4 MB
    uint4* Bp = (uint4*)(ws + off);          off += (size_t)2048 * 16;          // 32 KB
    float* dinv = (float*)(ws + off);        off += (size_t)N_NODES * 4;
    int* rowptr = (int*)(ws + off);          off += (size_t)(N_NODES + 1) * 4;
    int* cntm = (int*)(ws + off);            off += (size_t)NBUCK * NBF * 4;    // 400 KB
    int* offs = (int*)(ws + off);            off += (size_t)NBUCK * NBF * 4;    // 400 KB
    int* tot = (int*)(ws + off);             off += (size_t)NBUCK * 4;
    int* bbase = (int*)(ws + off);           off += (size_t)NBUCK * 4;
    float* pooled = (float*)(ws + off);      off += (size_t)N_GRAPHS * HID * 4;
    int* cnt = (int*)(ws + off);             off += (size_t)N_GRAPHS * 4;
    // aliases: staging lives in h2b (dead until gather2 writes h2);
    // xs (3.2 MB) + agg (6.4 MB) live in mbuf; fp8 messages overwrite mbuf after agg is dead
    unsigned* staging = h2b;
    unsigned* xs = mbuf;
    float* agg = (float*)(mbuf + (size_t)N_NODES * 8);
    unsigned char* mfp8 = (unsigned char*)mbuf;

    // graph preprocessing (zero global atomics)
    k_init<<<(N_GRAPHS * HID + 255) / 256, 256, 0, stream>>>(pooled);
    k_hist<<<NBF, 256, 0, stream>>>(dst, cntm);
    k_btot<<<NBUCK, 256, 0, stream>>>(cntm, tot);
    k_bscan<<<1, 256, 0, stream>>>(tot, bbase, rowptr);
    k_offs<<<NBUCK, NBF, 0, stream>>>(cntm, bbase, offs);
    k_partition<<<NBF, 256, 0, stream>>>(src, dst, offs, staging);
    k_fuse<<<NBUCK, 256, 0, stream>>>(staging, bbase, rowptr, dinv, csr_src);
    k_w2pack<<<8, 256, 0, stream>>>(W2, Bp);

    // layer 1: aggregate-first (15-ch rows)
    k_prescale<<<(N_NODES * 8 + 255) / 256, 256, 0, stream>>>(x, dinv, xs);
    k_gather15<<<(N_NODES + 3) / 4, 256, 0, stream>>>(rowptr, csr_src, xs, dinv, agg);
    k_xform1c<<<N_NODES / 32, 256, 0, stream>>>(agg, W1, b1, h1b);

    // layer 2: MFMA transform (reads h1b, writes fp8 into mbuf; agg dead) + fp8 gather
    k_xform2<<<(N_NODES + 63) / 64, 256, 0, stream>>>(h1b, Bp, dinv, mfp8);
    k_gather<<<(N_NODES + 3) / 4, 256, 0, stream>>>(rowptr, csr_src, (const unsigned*)mfp8, b2, dinv, h2b);

    // pooling + classifier
    k_cnt<<<1, 64, 0, stream>>>(batch, cnt);
    k_pool<<<(N_NODES + POOL_CHUNK - 1) / POOL_CHUNK, 256, 0, stream>>>(h2b, batch, pooled);
    k_final<<<N_GRAPHS, 128, 0, stream>>>(pooled, cnt, Wf, bf, out);
}

// Round 19
// 215.498 us; speedup vs baseline: 1.0909x; 1.0364x over previous
//
#include <hip/hip_runtime.h>

#define N_NODES 100000
#define N_EDGES 1600000
#define N_GRAPHS 64
#define IN_CH 15
#define HID 128
#define NCLS 11

// bucketed CSR geometry
#define NBUCK 196            // ceil(100000 / 512), bucket = dst >> 9
#define NBF 512              // partition blocks
#define EPB (N_EDGES / NBF)  // 3125 edges per block

using short8 = __attribute__((ext_vector_type(8))) short;
using f32x4 = __attribute__((ext_vector_type(4))) float;
using f32x2 = __attribute__((ext_vector_type(2))) float;

// ---- bf16 pack/unpack (RNE) ----
__device__ __forceinline__ unsigned short f2bf(float f) {
    unsigned u = __builtin_bit_cast(unsigned, f);
    u += 0x7FFF + ((u >> 16) & 1);
    return (unsigned short)(u >> 16);
}
__device__ __forceinline__ unsigned packbf(float a, float b) {
    return (unsigned)f2bf(a) | ((unsigned)f2bf(b) << 16);
}
__device__ __forceinline__ float2 unpackbf(unsigned v) {
    float2 r;
    unsigned lo = v << 16;
    unsigned hi = v & 0xFFFF0000u;
    r.x = __builtin_bit_cast(float, lo);
    r.y = __builtin_bit_cast(float, hi);
    return r;
}

// ---- fp8 e4m3 (OCP, gfx950 HW converts) ----
__device__ __forceinline__ unsigned char f2fp8(float f) {
    return (unsigned char)(__builtin_amdgcn_cvt_pk_fp8_f32(f, f, 0, false) & 0xFF);
}

// ---------------- per-block bucket histogram (LDS only, NO global atomics) ----------------
__global__ __launch_bounds__(256) void k_hist(const int* __restrict__ dst,
                                              int* __restrict__ cntm) {
    __shared__ int hist[NBUCK];
    int t = threadIdx.x;
    for (int i = t; i < NBUCK; i += 256) hist[i] = 0;
    __syncthreads();
    int base = blockIdx.x * EPB;
#pragma unroll
    for (int i = 0; i < (EPB + 255) / 256; ++i) {
        int e = i * 256 + t;
        if (e < EPB) atomicAdd(&hist[dst[base + e] >> 9], 1);
    }
    __syncthreads();
    for (int b = t; b < NBUCK; b += 256)
        cntm[b * NBF + blockIdx.x] = hist[b];
}

// ---------------- bucket totals: reduce each cntm row ----------------
__global__ __launch_bounds__(256) void k_btot(const int* __restrict__ cntm,
                                              int* __restrict__ tot) {
    __shared__ int red[256];
    int b = blockIdx.x, t = threadIdx.x;
    red[t] = cntm[b * NBF + t] + cntm[b * NBF + t + 256];
    __syncthreads();
    for (int off = 128; off > 0; off >>= 1) {
        if (t < off) red[t] += red[t + off];
        __syncthreads();
    }
    if (t == 0) tot[b] = red[0];
}

// ---------------- scan 196 bucket totals -> bbase; rowptr[N]=E; zero pooled ----------------
__global__ __launch_bounds__(256) void k_bscan(const int* __restrict__ tot,
                                               int* __restrict__ bbase,
                                               int* __restrict__ rowptr,
                                               float* __restrict__ pooled) {
    __shared__ int arr[256];
    int t = threadIdx.x;
    arr[t] = (t < NBUCK) ? tot[t] : 0;
    __syncthreads();
    for (int off = 1; off < 256; off <<= 1) {
        int v = (t >= off) ? arr[t - off] : 0;
        __syncthreads();
        arr[t] += v;
        __syncthreads();
    }
    if (t < NBUCK) bbase[t] = (t == 0) ? 0 : arr[t - 1];
    if (t == 0) rowptr[N_NODES] = N_EDGES;
    for (int i = t; i < N_GRAPHS * HID; i += 256) pooled[i] = 0.f;
}

// ---------------- per-(bucket,block) partition offsets ----------------
__global__ __launch_bounds__(NBF) void k_offs(const int* __restrict__ cntm,
                                              const int* __restrict__ bbase,
                                              int* __restrict__ offs) {
    __shared__ int arr[NBF];
    int b = blockIdx.x, t = threadIdx.x;
    arr[t] = cntm[b * NBF + t];
    __syncthreads();
    for (int off = 1; off < NBF; off <<= 1) {
        int v = (t >= off) ? arr[t - off] : 0;
        __syncthreads();
        arr[t] += v;
        __syncthreads();
    }
    offs[b * NBF + t] = bbase[b] + ((t == 0) ? 0 : arr[t - 1]);
}

// ---------------- partition: edges -> staging, grouped by 512-node bucket ----------------
// packed: (dst & 511) << 17 | src   (src < 2^17)
__global__ __launch_bounds__(256) void k_partition(const int* __restrict__ src,
                                                   const int* __restrict__ dst,
                                                   const int* __restrict__ offs,
                                                   unsigned* __restrict__ staging) {
    __shared__ int cur[NBUCK];
    int t = threadIdx.x;
    for (int b = t; b < NBUCK; b += 256) cur[b] = offs[b * NBF + blockIdx.x];
    __syncthreads();
    int base = blockIdx.x * EPB;
#pragma unroll
    for (int i = 0; i < (EPB + 255) / 256; ++i) {
        int e = i * 256 + t;
        if (e < EPB) {
            int d = dst[base + e];
            int s = src[base + e];
            int slot = atomicAdd(&cur[d >> 9], 1);
            staging[slot] = ((unsigned)(d & 511) << 17) | (unsigned)s;
        }
    }
}

// ---------------- fuse: per-bucket node histogram -> rowptr, dinv; then csr scatter ----------------
__global__ __launch_bounds__(256) void k_fuse(const unsigned* __restrict__ staging,
                                              const int* __restrict__ bbase,
                                              int* __restrict__ rowptr,
                                              float* __restrict__ dinv,
                                              int* __restrict__ csr_src) {
    __shared__ int cnt[512];
    __shared__ int cur[512];
    __shared__ int arr[256];
    int b = blockIdx.x, t = threadIdx.x;
    cnt[t] = 0; cnt[t + 256] = 0;
    __syncthreads();
    int beg = bbase[b];
    int end = (b == NBUCK - 1) ? N_EDGES : bbase[b + 1];
    for (int e = beg + t; e < end; e += 256)
        atomicAdd(&cnt[staging[e] >> 17], 1);
    __syncthreads();
    int c0 = cnt[2 * t], c1 = cnt[2 * t + 1];
    arr[t] = c0 + c1;
    __syncthreads();
    for (int off = 1; off < 256; off <<= 1) {
        int v = (t >= off) ? arr[t - off] : 0;
        __syncthreads();
        arr[t] += v;
        __syncthreads();
    }
    int excl = (t == 0) ? 0 : arr[t - 1];
    int p0 = beg + excl;
    int p1 = p0 + c0;
    cur[2 * t] = p0;
    cur[2 * t + 1] = p1;
    int n0 = b << 9;
    int n = n0 + 2 * t;
    if (n < N_NODES) { rowptr[n] = p0; dinv[n] = rsqrtf((float)(c0 + 1)); }
    n = n0 + 2 * t + 1;
    if (n < N_NODES) { rowptr[n] = p1; dinv[n] = rsqrtf((float)(c1 + 1)); }
    __syncthreads();
    for (int e = beg + t; e < end; e += 256) {
        unsigned v = staging[e];
        int pos = atomicAdd(&cur[v >> 17], 1);
        csr_src[pos] = (int)(v & 0x1FFFFu);
    }
}

// ---------------- W2 -> MFMA B-fragment layout, bf16 ----------------
__global__ __launch_bounds__(256) void k_w2pack(const float* __restrict__ W2,
                                                uint4* __restrict__ Bp) {
    int i = blockIdx.x * 256 + threadIdx.x;  // 2048 slots
    if (i >= 2048) return;
    int lane = i & 63;
    int kb = (i >> 6) & 3;
    int ct = i >> 8;
    int col = ct * 16 + (lane & 15);
    int k0 = kb * 32 + ((lane >> 4) & 3) * 8;
    unsigned w[4];
#pragma unroll
    for (int p = 0; p < 4; ++p) {
        int k = k0 + 2 * p;
        w[p] = packbf(W2[k * HID + col], W2[(k + 1) * HID + col]);
    }
    Bp[i] = make_uint4(w[0], w[1], w[2], w[3]);
}

// ---------------- prescale: xs[n][16] = bf16(x[n][ch] * dinv[n]), ch15 = 0 ----------------
__global__ __launch_bounds__(256) void k_prescale(const float* __restrict__ x,
                                                  const float* __restrict__ dinv,
                                                  unsigned* __restrict__ xs) {
    int i = blockIdx.x * 256 + threadIdx.x;  // one thread per (node, ch-pair)
    if (i >= N_NODES * 8) return;
    int n = i >> 3, p = i & 7;
    float dv = dinv[n];
    int c0 = 2 * p, c1 = c0 + 1;
    float a = x[(size_t)n * IN_CH + c0] * dv;                       // c0 <= 14 always
    float b = (c1 < IN_CH) ? x[(size_t)n * IN_CH + c1] * dv : 0.f;  // pad ch15
    xs[i] = packbf(a, b);
}

// ---------------- l1fused: gather15 + xform1 in one kernel ----------------
// One wave per node. Edge loop: 8 lane-groups x channel-pair cp = l&7; butterfly reduce
// leaves EVERY lane with the full edge-sum for its cp. Self+dinv applied in-register;
// 16 shfls broadcast all 16 agg channels within each 8-lane group; lane computes its
// 2 h1 columns with register W1. Kills the 12.8MB agg round trip + one launch.
__global__ __launch_bounds__(256) void k_l1fused(const int* __restrict__ rowptr,
                                                 const int* __restrict__ csr_src,
                                                 const unsigned* __restrict__ xs,
                                                 const float* __restrict__ dinv,
                                                 const float* __restrict__ W1,
                                                 const float* __restrict__ b1,
                                                 unsigned* __restrict__ h1b) {
    int wave = (blockIdx.x * 256 + threadIdx.x) >> 6;
    if (wave >= N_NODES) return;
    unsigned n = (unsigned)wave;
    int l = threadIdx.x & 63;
    int g = l >> 3;
    unsigned cp = (unsigned)(l & 7);
    float2 w[IN_CH];
#pragma unroll
    for (int k = 0; k < IN_CH; ++k) w[k] = *(const float2*)&W1[k * HID + l * 2];
    float2 bb = *(const float2*)&b1[l * 2];
    int beg = rowptr[n], end = rowptr[n + 1];
    float2 acc = make_float2(0.f, 0.f);
    for (int e = beg + g; e < end; e += 8) {
        unsigned s = (unsigned)csr_src[e];
        float2 v = unpackbf(xs[s * 8u + cp]);
        acc.x += v.x; acc.y += v.y;
    }
#pragma unroll
    for (int off = 8; off < 64; off <<= 1) {
        acc.x += __shfl_xor(acc.x, off, 64);
        acc.y += __shfl_xor(acc.y, off, 64);
    }
    // self term + dinv (valid in every lane for its cp)
    float2 s = unpackbf(xs[n * 8u + cp]);
    float dv = dinv[n];
    float ax = (acc.x + s.x) * dv;
    float ay = (acc.y + s.y) * dv;
    // broadcast 16 agg channels within the 8-lane group; accumulate into 2 output cols
    float a0 = bb.x, a1 = bb.y;
    int gbase = l & 56;
#pragma unroll
    for (int p = 0; p < 8; ++p) {
        float vx = __shfl(ax, gbase | p, 64);
        float vy = __shfl(ay, gbase | p, 64);
        int k0 = 2 * p;
        a0 += vx * w[k0].x; a1 += vx * w[k0].y;
        if (k0 + 1 < IN_CH) { a0 += vy * w[k0 + 1].x; a1 += vy * w[k0 + 1].y; }
    }
    h1b[(size_t)n * 64 + l] = packbf(fmaxf(a0, 0.f), fmaxf(a1, 0.f));
}

// ---------------- layer-2 transform via MFMA: m = fp8e4m3((h1 @ W2) * dinv), row-major [n][128] ----------------
__global__ __launch_bounds__(256) void k_xform2(const unsigned* __restrict__ h1b,
                                                const uint4* __restrict__ Bp,
                                                const float* __restrict__ dinv,
                                                unsigned char* __restrict__ mout) {
    int lane = threadIdx.x & 63;
    int wid = threadIdx.x >> 6;
    int row0 = blockIdx.x * 64 + wid * 16;
    int arow = row0 + (lane & 15);
    const uint4* hbase = (const uint4*)h1b;
    uint4 a_u[4];
#pragma unroll
    for (int kb = 0; kb < 4; ++kb)
        a_u[kb] = hbase[(size_t)arow * 16 + kb * 4 + (lane >> 4)];
    int rbase = row0 + (lane >> 4) * 4;
    float dv[4];
#pragma unroll
    for (int j = 0; j < 4; ++j) dv[j] = dinv[min(rbase + j, N_NODES - 1)];
#pragma unroll
    for (int ct = 0; ct < 8; ++ct) {
        f32x4 acc = {0.f, 0.f, 0.f, 0.f};
#pragma unroll
        for (int kb = 0; kb < 4; ++kb) {
            uint4 b_u = Bp[(ct * 4 + kb) * 64 + lane];
            acc = __builtin_amdgcn_mfma_f32_16x16x32_bf16(
                __builtin_bit_cast(short8, a_u[kb]),
                __builtin_bit_cast(short8, b_u), acc, 0, 0, 0);
        }
        int col = ct * 16 + (lane & 15);
#pragma unroll
        for (int j = 0; j < 4; ++j) {
            int r = rbase + j;
            if (r < N_NODES) mout[(size_t)r * HID + col] = f2fp8(acc[j] * dv[j]);
        }
    }
}

// ---------------- gather (layer 2): out = bf16(relu(dinv*(m[n]+sum m[src])+b)) ----------------
// one wave per node; 32 lanes per 128B fp8 row (lane owns 4 channels via uint load);
// wave halves process even/odd edges. At random-access service floor (~55us) — do not touch.
__global__ __launch_bounds__(256) void k_gather(const int* __restrict__ rowptr,
                                                const int* __restrict__ csr_src,
                                                const unsigned* __restrict__ m,
                                                const float* __restrict__ bias,
                                                const float* __restrict__ dinv,
                                                unsigned* __restrict__ outh) {
    int wave = (blockIdx.x * 256 + threadIdx.x) >> 6;
    if (wave >= N_NODES) return;
    unsigned n = (unsigned)wave;
    int lane = threadIdx.x & 63;
    int half = lane >> 5;
    unsigned li = (unsigned)(lane & 31);
    int beg = rowptr[n], end = rowptr[n + 1];
    f32x4 acc = {0.f, 0.f, 0.f, 0.f};
    if (half == 0) {  // self-loop term once
        unsigned u = m[n * 32u + li];
        f32x2 lo = __builtin_amdgcn_cvt_pk_f32_fp8((int)u, false);
        f32x2 hi = __builtin_amdgcn_cvt_pk_f32_fp8((int)u, true);
        acc[0] += lo[0]; acc[1] += lo[1]; acc[2] += hi[0]; acc[3] += hi[1];
    }
    int e = beg + half;
    for (; e + 6 < end; e += 8) {  // 4 edges per half in flight (8 per wave)
        unsigned o0 = (unsigned)csr_src[e + 0] * 32u + li;
        unsigned o1 = (unsigned)csr_src[e + 2] * 32u + li;
        unsigned o2 = (unsigned)csr_src[e + 4] * 32u + li;
        unsigned o3 = (unsigned)csr_src[e + 6] * 32u + li;
        unsigned u0 = m[o0];
        unsigned u1 = m[o1];
        unsigned u2 = m[o2];
        unsigned u3 = m[o3];
        f32x2 l0 = __builtin_amdgcn_cvt_pk_f32_fp8((int)u0, false);
        f32x2 h0 = __builtin_amdgcn_cvt_pk_f32_fp8((int)u0, true);
        f32x2 l1 = __builtin_amdgcn_cvt_pk_f32_fp8((int)u1, false);
        f32x2 h1 = __builtin_amdgcn_cvt_pk_f32_fp8((int)u1, true);
        f32x2 l2 = __builtin_amdgcn_cvt_pk_f32_fp8((int)u2, false);
        f32x2 h2 = __builtin_amdgcn_cvt_pk_f32_fp8((int)u2, true);
        f32x2 l3 = __builtin_amdgcn_cvt_pk_f32_fp8((int)u3, false);
        f32x2 h3 = __builtin_amdgcn_cvt_pk_f32_fp8((int)u3, true);
        acc[0] += l0[0] + l1[0] + l2[0] + l3[0];
        acc[1] += l0[1] + l1[1] + l2[1] + l3[1];
        acc[2] += h0[0] + h1[0] + h2[0] + h3[0];
        acc[3] += h0[1] + h1[1] + h2[1] + h3[1];
    }
    for (; e < end; e += 2) {
        unsigned u = m[(unsigned)csr_src[e] * 32u + li];
        f32x2 lo = __builtin_amdgcn_cvt_pk_f32_fp8((int)u, false);
        f32x2 hi = __builtin_amdgcn_cvt_pk_f32_fp8((int)u, true);
        acc[0] += lo[0]; acc[1] += lo[1]; acc[2] += hi[0]; acc[3] += hi[1];
    }
    // cross-half reduce (even-edge half + odd-edge half)
#pragma unroll
    for (int j = 0; j < 4; ++j) acc[j] += __shfl_xor(acc[j], 32, 64);
    if (half == 0) {
        float dv = dinv[n];
        float4 b = *(const float4*)&bias[li * 4u];
        float r0 = fmaxf(acc[0] * dv + b.x, 0.f);
        float r1 = fmaxf(acc[1] * dv + b.y, 0.f);
        float r2 = fmaxf(acc[2] * dv + b.z, 0.f);
        float r3 = fmaxf(acc[3] * dv + b.w, 0.f);
        uint2 ov;
        ov.x = packbf(r0, r1);
        ov.y = packbf(r2, r3);
        *(uint2*)&outh[n * 64u + li * 2u] = ov;
    }
}

// ---------------- pooled sums over packed bf16 h2 ----------------
#define POOL_CHUNK 128
__global__ __launch_bounds__(256) void k_pool(const unsigned* __restrict__ h,
                                              const int* __restrict__ batch,
                                              float* __restrict__ pooled) {
    int t = threadIdx.x;
    int lane = t & 63;
    int grp = t >> 6;  // 0..3
    int start = blockIdx.x * POOL_CHUNK;
    int end = min(start + POOL_CHUNK, N_NODES);
    float2 acc = make_float2(0.f, 0.f);
    int cur = -1;
    for (int n = start + grp; n < end; n += 4) {
        int g = batch[n];
        if (g != cur) {
            if (cur >= 0) {
                atomicAdd(&pooled[cur * HID + lane * 2], acc.x);
                atomicAdd(&pooled[cur * HID + lane * 2 + 1], acc.y);
            }
            acc = make_float2(0.f, 0.f);
            cur = g;
        }
        float2 v = unpackbf(h[(unsigned)n * 64u + (unsigned)lane]);
        acc.x += v.x; acc.y += v.y;
    }
    if (cur >= 0) {
        atomicAdd(&pooled[cur * HID + lane * 2], acc.x);
        atomicAdd(&pooled[cur * HID + lane * 2 + 1], acc.y);
    }
}

// ---------------- final: out = (pooled/cnt) @ Wf + bf; cnt via inline binary search ----------------
__global__ __launch_bounds__(128) void k_final(const float* __restrict__ pooled,
                                               const int* __restrict__ batch,
                                               const float* __restrict__ Wf,
                                               const float* __restrict__ bf,
                                               float* __restrict__ out) {
    __shared__ float p[HID];
    __shared__ int bnd[2];
    int g = blockIdx.x, t = threadIdx.x;
    if (t < 2) {
        int key = g + t;
        int lo = 0, hi = N_NODES;
        while (lo < hi) { int mid = (lo + hi) >> 1; if (batch[mid] < key) lo = mid + 1; else hi = mid; }
        bnd[t] = lo;
    }
    __syncthreads();
    float inv = 1.f / fmaxf((float)(bnd[1] - bnd[0]), 1.f);
    p[t] = pooled[g * HID + t] * inv;
    __syncthreads();
    if (t < NCLS) {
        float acc = bf[t];
        for (int k = 0; k < HID; ++k) acc += p[k] * Wf[k * NCLS + t];
        out[g * NCLS + t] = acc;
    }
}

extern "C" void kernel_launch(void* const* d_in, const int* in_sizes, int n_in,
                              void* d_out, int out_size, void* d_ws, size_t ws_size,
                              hipStream_t stream) {
    const float* x   = (const float*)d_in[0];
    const int*   ei  = (const int*)d_in[1];   // [2][E] flat
    const int*   src = ei;
    const int*   dst = ei + N_EDGES;
    const int*   batch = (const int*)d_in[2];
    const float* W1 = (const float*)d_in[3];
    const float* b1 = (const float*)d_in[4];
    const float* W2 = (const float*)d_in[5];
    const float* b2 = (const float*)d_in[6];
    const float* Wf = (const float*)d_in[7];
    const float* bf = (const float*)d_in[8];
    float* out = (float*)d_out;

    char* ws = (char*)d_ws;
    size_t off = 0;
    unsigned* mbuf = (unsigned*)(ws + off);  off += (size_t)N_NODES * 64 * 4;   // 25.6 MB: xs early, fp8 messages late
    unsigned* h1b = (unsigned*)(ws + off);   off += (size_t)N_NODES * 64 * 4;   // 25.6 MB bf16 h1
    unsigned* h2b = (unsigned*)(ws + off);   off += (size_t)N_NODES * 64 * 4;   // 25.6 MB bf16 h2 / staging
    int* csr_src = (int*)(ws + off);         off += (size_t)N_EDGES * 4;        // 6.4 MB
    uint4* Bp = (uint4*)(ws + off);          off += (size_t)2048 * 16;          // 32 KB
    float* dinv = (float*)(ws + off);        off += (size_t)N_NODES * 4;
    int* rowptr = (int*)(ws + off);          off += (size_t)(N_NODES + 1) * 4;
    int* cntm = (int*)(ws + off);            off += (size_t)NBUCK * NBF * 4;    // 400 KB
    int* offs = (int*)(ws + off);            off += (size_t)NBUCK * NBF * 4;    // 400 KB
    int* tot = (int*)(ws + off);             off += (size_t)NBUCK * 4;
    int* bbase = (int*)(ws + off);           off += (size_t)NBUCK * 4;
    float* pooled = (float*)(ws + off);      off += (size_t)N_GRAPHS * HID * 4;
    // aliases: staging lives in h2b (dead until gather2 writes h2);
    // xs (3.2 MB) lives in mbuf; fp8 messages overwrite mbuf after xs is dead (post-l1fused)
    unsigned* staging = h2b;
    unsigned* xs = mbuf + (size_t)N_NODES * 16;  // keep xs clear of fp8 region? fp8 uses first 12.8MB; xs at +6.4MB.. see note
    // NOTE: fp8 messages occupy mbuf[0 .. 3.2M uints); xs occupies mbuf[1.6M .. 2.4M uints)
    // -> OVERLAP. Place xs at the END of mbuf instead: last 800k uints of the 6.4M-uint buffer.
    xs = mbuf + ((size_t)N_NODES * 64 - (size_t)N_NODES * 8);
    unsigned char* mfp8 = (unsigned char*)mbuf;  // 12.8 MB = first 3.2M uints; xs at +5.6M uints: disjoint

    // graph preprocessing (zero global atomics)
    k_hist<<<NBF, 256, 0, stream>>>(dst, cntm);
    k_btot<<<NBUCK, 256, 0, stream>>>(cntm, tot);
    k_bscan<<<1, 256, 0, stream>>>(tot, bbase, rowptr, pooled);
    k_offs<<<NBUCK, NBF, 0, stream>>>(cntm, bbase, offs);
    k_partition<<<NBF, 256, 0, stream>>>(src, dst, offs, staging);
    k_fuse<<<NBUCK, 256, 0, stream>>>(staging, bbase, rowptr, dinv, csr_src);
    k_w2pack<<<8, 256, 0, stream>>>(W2, Bp);

    // layer 1: prescale + fused gather/transform (agg round trip eliminated)
    k_prescale<<<(N_NODES * 8 + 255) / 256, 256, 0, stream>>>(x, dinv, xs);
    k_l1fused<<<(N_NODES + 3) / 4, 256, 0, stream>>>(rowptr, csr_src, xs, dinv, W1, b1, h1b);

    // layer 2: MFMA transform (reads h1b, writes fp8 into mbuf head; xs in mbuf tail stays live until l1fused done) + fp8 gather
    k_xform2<<<(N_NODES + 63) / 64, 256, 0, stream>>>(h1b, Bp, dinv, mfp8);
    k_gather<<<(N_NODES + 3) / 4, 256, 0, stream>>>(rowptr, csr_src, (const unsigned*)mfp8, b2, dinv, h2b);

    // pooling + classifier (cnt folded into k_final)
    k_pool<<<(N_NODES + POOL_CHUNK - 1) / POOL_CHUNK, 256, 0, stream>>>(h2b, batch, pooled);
    k_final<<<N_GRAPHS, 128, 0, stream>>>(pooled, batch, Wf, bf, out);
}